// Round 4
// baseline (1754.783 us; speedup 1.0000x reference)
//
#include <hip/hip_runtime.h>
#include <math.h>

typedef _Float16 f16;
typedef _Float16 f16x8 __attribute__((ext_vector_type(8)));
typedef float    f32x4 __attribute__((ext_vector_type(4)));

#define NBLK 256
#define NTHR 512
#define MROW 64

// fragment regions in d_ws (1 frag = 512 fp16 = 1KB; lane l holds 8 fp16 at l*8)
// B-frag for v_mfma_f32_16x16x32_f16: lane l -> col j = jb + (l&15), k = kb + (l>>4)*8 + jj
#define DEC_F 0      // (jf<<5 | st<<3 | kc)           jf 0..15, st 0..3, kc 0..7
#define FC1_F 512    // 512 + jf*8 + kc
#define FC2_F 640    // 640 + kc
#define ENC_F 648    // 648 + jf*36 + (x: kc*3+st | 12 + kc*3+st)
#define TOT_F 1224
#define TOT_E (TOT_F*512)   // 626,688 fp16 = 1.25 MB

__device__ __forceinline__ float sigm(float v){
  return __fdividef(1.0f, 1.0f + __expf(-v));
}
__device__ __forceinline__ float tanh_f(float v){
  float t = fminf(v, 8.0f);
  float e = __expf(2.0f * t);
  return 1.0f - 2.0f * __fdividef(1.0f, e + 1.0f);
}
// LDS element index with XOR swizzle (k bits [3:5] ^ row&7)
__device__ __forceinline__ int eH(int row, int k){ return row*256 + (k ^ ((row & 7) << 3)); }
__device__ __forceinline__ int eX(int row, int k){ return row*128 + (k ^ ((row & 7) << 3)); }

// ---------------- prep: pack all weights as fp16 B-fragments into d_ws (validated r2/r3) ----------------
__global__ void prep_pack(const float* __restrict__ eWih, const float* __restrict__ eWhh,
                          const float* __restrict__ dWih, const float* __restrict__ dWhh,
                          const float* __restrict__ f1W,  const float* __restrict__ f2W,
                          f16* __restrict__ ws16)
{
  int idx = blockIdx.x * 256 + threadIdx.x;
  if (idx >= TOT_E) return;
  int frag = idx >> 9;
  int lo   = idx & 511;
  int l    = lo >> 3;
  int jj   = lo & 7;
  int c16  = l & 15;
  int q    = l >> 4;
  float v = 0.0f;
  if (frag < FC1_F){                       // decoder GRU
    int jf = frag >> 5, st = (frag >> 3) & 3, kc = frag & 7;
    int j = jf*16 + c16, k = kc*32 + q*8 + jj;
    if      (st == 0) v = dWih[j*256 + k]        + dWhh[j*256 + k];          // r (presummed)
    else if (st == 1) v = dWih[(256+j)*256 + k]  + dWhh[(256+j)*256 + k];    // z (presummed)
    else if (st == 2) v = dWih[(512+j)*256 + k];                             // in
    else              v = dWhh[(512+j)*256 + k];                             // hn
  } else if (frag < FC2_F){                // fc1
    int f = frag - FC1_F, jf = f >> 3, kc = f & 7;
    int j = jf*16 + c16, k = kc*32 + q*8 + jj;
    v = f1W[j*256 + k];
  } else if (frag < ENC_F){                // fc2 (cols >=2 zero-padded)
    int kc = frag - FC2_F;
    int j = c16, k = kc*32 + q*8 + jj;
    v = (j < 2) ? f2W[j*256 + k] : 0.0f;
  } else {                                 // encoder GRU
    int f = frag - ENC_F, jf = f / 36, r = f % 36;
    int j = jf*16 + c16;
    if (r < 12){ int kc = r/3, st = r%3; int k = kc*32 + q*8 + jj;
      v = eWih[(st*256 + j)*128 + k]; }
    else { r -= 12; int kc = r/3, st = r%3; int k = kc*32 + q*8 + jj;
      v = eWhh[(st*256 + j)*256 + k]; }
  }
  ws16[idx] = (f16)v;
}

// ---------------- fused persistent kernel ----------------
__global__ __launch_bounds__(NTHR, 2)
void fused_net(const float* __restrict__ x,
               const float* __restrict__ emW, const float* __restrict__ emb_,
               const float* __restrict__ evW, const float* __restrict__ evb,
               const float* __restrict__ ebih, const float* __restrict__ ebhh,
               const float* __restrict__ dbih, const float* __restrict__ dbhh,
               const float* __restrict__ f1b, const float* __restrict__ f2b,
               const f16* __restrict__ ws16, float* __restrict__ out)
{
  __shared__ __align__(16) f16 hA[16384];   // [64][256] fp16, swizzled
  __shared__ __align__(16) f16 hB[16384];
  __shared__ __align__(16) f16 hC[16384];   // fc1-out (decoder); xb [64][128] (encoder)

  const int tid = threadIdx.x;
  const int r0  = blockIdx.x * MROW;
  const int l   = tid & 63;
  const int w   = tid >> 6;        // wave 0..7
  const int c16 = l & 15;
  const int q   = l >> 4;
  const int swm = (c16 & 7) << 3;  // per-lane swizzle mask

  f16* hp = hA;
  f16* hq = hB;
  f16* xb = hC;

  // precomputed element offsets for A-frag ds_reads (rf adds rf*4096 elements;
  // row = rf*16 + c16, rf*16 = 0 mod 8 so swizzle mask is rf-invariant)
  int aoff[8], xoff[4];
  #pragma unroll
  for (int kc = 0; kc < 8; ++kc) aoff[kc] = c16*256 + ((kc*32 + q*8) ^ swm);
  #pragma unroll
  for (int kc = 0; kc < 4; ++kc) xoff[kc] = c16*128 + ((kc*32 + q*8) ^ swm);

  for (int i = tid; i < 16384; i += NTHR) hA[i] = (f16)0.0f;   // h0 = 0

  // hoisted per-lane biases (wave w owns col-frags 2w, 2w+1)
  float ebr[2], ebz[2], ebi[2], ebh[2];
  float dbr[2], dbz[2], dbi[2], dbh[2], f1bb[2];
  #pragma unroll
  for (int jfi = 0; jfi < 2; ++jfi){
    int j = (2*w + jfi)*16 + c16;
    ebr[jfi] = ebih[j]       + ebhh[j];
    ebz[jfi] = ebih[256 + j] + ebhh[256 + j];
    ebi[jfi] = ebih[512 + j];
    ebh[jfi] = ebhh[512 + j];
    dbr[jfi] = dbih[j]       + dbhh[j];
    dbz[jfi] = dbih[256 + j] + dbhh[256 + j];
    dbi[jfi] = dbih[512 + j];
    dbh[jfi] = dbhh[512 + j];
    f1bb[jfi] = f1b[j];
  }
  const float f2bb = (c16 < 2) ? f2b[c16] : 0.0f;
  __syncthreads();

  // =============== ENCODER: 9 GRU steps ===============
  #pragma unroll 1
  for (int t = 0; t < 9; ++t){
    { // xt = tanh(embedding) -> xb
      int e  = tid & 127;
      int rq = tid >> 7;                      // 0..3 -> rows rq*16..+15
      const float* Wp = (t < 8) ? (evW + e*6) : (emW + e*6);
      float bb = (t < 8) ? evb[e] : emb_[e];
      float w0 = Wp[0], w1 = Wp[1], w2 = Wp[2], w3 = Wp[3], w4 = Wp[4], w5 = Wp[5];
      int xo = (t < 8) ? (6 + t*6) : 0;
      #pragma unroll 1
      for (int rr = 0; rr < 16; ++rr){
        int row = rq*16 + rr;
        const float* xs = x + (size_t)(r0 + row)*54 + xo;
        float a = bb + xs[0]*w0 + xs[1]*w1 + xs[2]*w2 + xs[3]*w3 + xs[4]*w4 + xs[5]*w5;
        xb[eX(row, e)] = (f16)tanh_f(a);
      }
    }
    __syncthreads();

    #pragma unroll 1
    for (int jfi = 0; jfi < 2; ++jfi){
      const int jf = 2*w + jfi;
      const f16* wpe = ws16 + (size_t)(ENC_F + jf*36)*512 + l*8;
      // burst all 36 B-frags into registers (x: 12, h: 24)
      f16x8 bv[36];
      #pragma unroll
      for (int i = 0; i < 36; ++i) bv[i] = *(const f16x8*)(wpe + i*512);

      f32x4 ar[4], az[4], an[4], ah[4];
      #pragma unroll
      for (int rf = 0; rf < 4; ++rf){ ar[rf] = 0.f; az[rf] = 0.f; an[rf] = 0.f; ah[rf] = 0.f; }

      #pragma unroll
      for (int kc = 0; kc < 4; ++kc){            // x-part, K=128
        f16x8 av[4];
        #pragma unroll
        for (int rf = 0; rf < 4; ++rf)
          av[rf] = *(const f16x8*)(xb + xoff[kc] + rf*2048);
        #pragma unroll
        for (int rf = 0; rf < 4; ++rf){
          ar[rf] = __builtin_amdgcn_mfma_f32_16x16x32_f16(av[rf], bv[kc*3+0], ar[rf], 0, 0, 0);
          az[rf] = __builtin_amdgcn_mfma_f32_16x16x32_f16(av[rf], bv[kc*3+1], az[rf], 0, 0, 0);
          an[rf] = __builtin_amdgcn_mfma_f32_16x16x32_f16(av[rf], bv[kc*3+2], an[rf], 0, 0, 0);
        }
      }
      #pragma unroll
      for (int kc = 0; kc < 8; ++kc){            // h-part, K=256
        f16x8 av[4];
        #pragma unroll
        for (int rf = 0; rf < 4; ++rf)
          av[rf] = *(const f16x8*)(hp + aoff[kc] + rf*4096);
        #pragma unroll
        for (int rf = 0; rf < 4; ++rf){
          ar[rf] = __builtin_amdgcn_mfma_f32_16x16x32_f16(av[rf], bv[12+kc*3+0], ar[rf], 0, 0, 0);
          az[rf] = __builtin_amdgcn_mfma_f32_16x16x32_f16(av[rf], bv[12+kc*3+1], az[rf], 0, 0, 0);
          ah[rf] = __builtin_amdgcn_mfma_f32_16x16x32_f16(av[rf], bv[12+kc*3+2], ah[rf], 0, 0, 0);
        }
      }
      int j = jf*16 + c16;
      #pragma unroll
      for (int rf = 0; rf < 4; ++rf){
        #pragma unroll
        for (int r = 0; r < 4; ++r){
          int row = rf*16 + q*4 + r;
          float rv = sigm(ar[rf][r] + ebr[jfi]);
          float zv = sigm(az[rf][r] + ebz[jfi]);
          float nv = tanh_f(an[rf][r] + ebi[jfi] + rv*(ah[rf][r] + ebh[jfi]));
          float ho = (float)hp[eH(row, j)];
          hq[eH(row, j)] = (f16)(nv + zv*(ho - nv));
        }
      }
    }
    __syncthreads();
    { f16* tmp = hp; hp = hq; hq = tmp; }
  }

  // =============== DECODER: 32 x (GRU + fc1 + fc2) ===============
  #pragma unroll 1
  for (int s = 0; s < 32; ++s){
    // ---- GRU: reads hp, writes h_new -> hq ----
    #pragma unroll 1
    for (int jfi = 0; jfi < 2; ++jfi){
      const int jf = 2*w + jfi;
      const f16* wpd = ws16 + (size_t)(jf*32)*512 + l*8;
      // burst all 32 B-frags (4 streams x 8 kc) into registers
      f16x8 bv[32];
      #pragma unroll
      for (int i = 0; i < 32; ++i) bv[i] = *(const f16x8*)(wpd + i*512);

      f32x4 ac[4][4];
      #pragma unroll
      for (int st = 0; st < 4; ++st)
        #pragma unroll
        for (int rf = 0; rf < 4; ++rf) ac[st][rf] = 0.f;

      #pragma unroll
      for (int kc = 0; kc < 8; ++kc){
        f16x8 av[4];
        #pragma unroll
        for (int rf = 0; rf < 4; ++rf)
          av[rf] = *(const f16x8*)(hp + aoff[kc] + rf*4096);
        #pragma unroll
        for (int st = 0; st < 4; ++st)
          #pragma unroll
          for (int rf = 0; rf < 4; ++rf)
            ac[st][rf] = __builtin_amdgcn_mfma_f32_16x16x32_f16(av[rf], bv[st*8+kc], ac[st][rf], 0, 0, 0);
      }
      int j = jf*16 + c16;
      #pragma unroll
      for (int rf = 0; rf < 4; ++rf){
        #pragma unroll
        for (int r = 0; r < 4; ++r){
          int row = rf*16 + q*4 + r;
          float rv = sigm(ac[0][rf][r] + dbr[jfi]);
          float zv = sigm(ac[1][rf][r] + dbz[jfi]);
          float nv = tanh_f(ac[2][rf][r] + dbi[jfi] + rv*(ac[3][rf][r] + dbh[jfi]));
          float ho = (float)hp[eH(row, j)];
          hq[eH(row, j)] = (f16)(nv + zv*(ho - nv));
        }
      }
    }
    __syncthreads();

    // ---- FC1: relu(h_new @ W1.T + b1): reads hq, writes -> hC (A-frags shared across jfi) ----
    {
      const f16* wp1 = ws16 + (size_t)(FC1_F + (2*w)*8)*512 + l*8;
      f16x8 bv1[16];
      #pragma unroll
      for (int i = 0; i < 16; ++i) bv1[i] = *(const f16x8*)(wp1 + i*512);  // jfi0: 0..7, jfi1: 8..15

      f32x4 a1[2][4];
      #pragma unroll
      for (int jfi = 0; jfi < 2; ++jfi)
        #pragma unroll
        for (int rf = 0; rf < 4; ++rf) a1[jfi][rf] = 0.f;

      #pragma unroll
      for (int kc = 0; kc < 8; ++kc){
        f16x8 av[4];
        #pragma unroll
        for (int rf = 0; rf < 4; ++rf)
          av[rf] = *(const f16x8*)(hq + aoff[kc] + rf*4096);
        #pragma unroll
        for (int jfi = 0; jfi < 2; ++jfi)
          #pragma unroll
          for (int rf = 0; rf < 4; ++rf)
            a1[jfi][rf] = __builtin_amdgcn_mfma_f32_16x16x32_f16(av[rf], bv1[jfi*8+kc], a1[jfi][rf], 0, 0, 0);
      }
      #pragma unroll
      for (int jfi = 0; jfi < 2; ++jfi){
        int j = (2*w + jfi)*16 + c16;
        #pragma unroll
        for (int rf = 0; rf < 4; ++rf)
          #pragma unroll
          for (int r = 0; r < 4; ++r){
            int row = rf*16 + q*4 + r;
            hC[eH(row, j)] = (f16)fmaxf(a1[jfi][rf][r] + f1bb[jfi], 0.0f);
          }
      }
    }
    __syncthreads();

    // ---- FC2 (waves 0-3, 16 rows each): y = tanh(hC @ W2.T + b2) -> out ----
    if (w < 4){
      const f16* wp2 = ws16 + (size_t)FC2_F*512 + l*8;
      f16x8 bv2[8];
      #pragma unroll
      for (int i = 0; i < 8; ++i) bv2[i] = *(const f16x8*)(wp2 + i*512);
      f32x4 a2 = 0.f;
      #pragma unroll
      for (int kc = 0; kc < 8; ++kc){
        f16x8 av = *(const f16x8*)(hC + aoff[kc] + w*4096);
        a2 = __builtin_amdgcn_mfma_f32_16x16x32_f16(av, bv2[kc], a2, 0, 0, 0);
      }
      if (c16 < 2){
        #pragma unroll
        for (int r = 0; r < 4; ++r){
          int row = w*16 + q*4 + r;
          out[((size_t)(r0 + row)*32 + s)*2 + c16] = tanh_f(a2[r] + f2bb);
        }
      }
    }
    // no barrier: next GRU reads hp(unchanged)/writes hq(dead), FC2 reads hC — disjoint;
    // next FC1's hC write is after next GRU's barrier.
    { f16* tmp = hp; hp = hq; hq = tmp; }
  }
}

extern "C" void kernel_launch(void* const* d_in, const int* in_sizes, int n_in,
                              void* d_out, int out_size, void* d_ws, size_t ws_size,
                              hipStream_t stream)
{
  (void)in_sizes; (void)n_in; (void)out_size; (void)ws_size;
  const float* x    = (const float*)d_in[0];
  const float* emW  = (const float*)d_in[1];
  const float* emb_ = (const float*)d_in[2];
  const float* evW  = (const float*)d_in[3];
  const float* evb  = (const float*)d_in[4];
  const float* eWih = (const float*)d_in[5];
  const float* eWhh = (const float*)d_in[6];
  const float* ebih = (const float*)d_in[7];
  const float* ebhh = (const float*)d_in[8];
  const float* dWih = (const float*)d_in[9];
  const float* dWhh = (const float*)d_in[10];
  const float* dbih = (const float*)d_in[11];
  const float* dbhh = (const float*)d_in[12];
  const float* f1W  = (const float*)d_in[13];
  const float* f1b  = (const float*)d_in[14];
  const float* f2W  = (const float*)d_in[15];
  const float* f2b  = (const float*)d_in[16];
  float* out = (float*)d_out;
  f16* ws16 = (f16*)d_ws;

  prep_pack<<<(TOT_E + 255)/256, 256, 0, stream>>>(eWih, eWhh, dWih, dWhh, f1W, f2W, ws16);
  fused_net<<<NBLK, NTHR, 0, stream>>>(x, emW, emb_, evW, evb, ebih, ebhh,
                                       dbih, dbhh, f1b, f2b, ws16, out);
}